// Round 8
// baseline (146.853 us; speedup 1.0000x reference)
//
#include <hip/hip_runtime.h>

typedef unsigned short u16;
typedef __attribute__((ext_vector_type(8))) short bf16x8;
typedef __attribute__((ext_vector_type(4))) float f32x4;

// Problem constants
constexpr int BB = 64;     // batch
constexpr int NN = 256;    // nodes
constexpr int SS = 1024;   // LP*P spatial (= F)
constexpr int FF = 1024;   // node feature dim
constexpr int HH = 512;    // hidden

// EDGE_TYPES = [AB,BA,AC,CA,BC,CB,AA,BB,CC]
// dst A edges {1,3,6}; dst B {0,5,7}; dst C {2,4,8}
__device__ const int d_eArr[3][3] = {{1, 3, 6}, {0, 5, 7}, {2, 4, 8}};
// muCat slot: for src type tp, (dst t) -> e' slot with src(eArr[t][e'])==tp
__device__ const int d_slotE[3][3] = {{2, 0, 0}, {0, 2, 1}, {1, 1, 2}};

__device__ __forceinline__ u16 f2bf(float f) {
    union { float f; unsigned u; } v; v.f = f;
    unsigned r = v.u + 0x7FFFu + ((v.u >> 16) & 1u);
    return (u16)(r >> 16);
}
__device__ __forceinline__ float bf2f(u16 h) {
    union { unsigned u; float f; } v; v.u = ((unsigned)h) << 16;
    return v.f;
}

typedef const __attribute__((address_space(1))) void gv_t;
typedef __attribute__((address_space(3))) void lv_t;
__device__ __forceinline__ void gl16(const void* g, void* l) {
    __builtin_amdgcn_global_load_lds((gv_t*)g, (lv_t*)l, 16, 0, 0);
}
// 16B-slot swizzle per LDS row
__device__ __forceinline__ int swzv(int r) { return (r ^ (r >> 2)) & 3; }

template<int N> __device__ __forceinline__ void waitvm();
template<> __device__ __forceinline__ void waitvm<0>()  { asm volatile("s_waitcnt vmcnt(0)" ::: "memory"); }
template<> __device__ __forceinline__ void waitvm<2>()  { asm volatile("s_waitcnt vmcnt(2)" ::: "memory"); }
template<> __device__ __forceinline__ void waitvm<4>()  { asm volatile("s_waitcnt vmcnt(4)" ::: "memory"); }
template<> __device__ __forceinline__ void waitvm<6>()  { asm volatile("s_waitcnt vmcnt(6)" ::: "memory"); }
template<> __device__ __forceinline__ void waitvm<8>()  { asm volatile("s_waitcnt vmcnt(8)" ::: "memory"); }
template<> __device__ __forceinline__ void waitvm<12>() { asm volatile("s_waitcnt vmcnt(12)" ::: "memory"); }

// ---------------------------------------------------------------------------
// Batched transpose fp32 -> bf16: out[b][c][r] = in[b][r][c]  (x only).
// High-TLP standalone kernel: 2048 blocks, no inter-phase serialization —
// this beats fusing the transpose into G1 (R6/R7 lesson: the fused version's
// per-iteration load->use distance of 1 K-step exposes ~500 cyc HBM latency).
// ---------------------------------------------------------------------------
__global__ __launch_bounds__(256)
void transpose_bf16(const float* __restrict__ in, u16* __restrict__ out, int R, int C) {
    __shared__ float tile[32][33];
    const int b = blockIdx.z;
    in  += (size_t)b * R * C;
    out += (size_t)b * R * C;
    const int c0 = blockIdx.x * 32, r0 = blockIdx.y * 32;
    const int x = threadIdx.x & 31, y = threadIdx.x >> 5;
#pragma unroll
    for (int k = 0; k < 4; ++k)
        tile[y + 8 * k][x] = in[(size_t)(r0 + y + 8 * k) * C + c0 + x];
    __syncthreads();
#pragma unroll
    for (int k = 0; k < 4; ++k)
        out[(size_t)(c0 + y + 8 * k) * R + r0 + x] = f2bf(tile[x][y + 8 * k]);
}

// ---------------------------------------------------------------------------
// Combined weight prep: W1T, W2T, WfT transposes + WlTcat + WsumT + blsum + c2
// ---------------------------------------------------------------------------
__device__ __forceinline__ void tr32(const float* __restrict__ in, u16* __restrict__ out,
                                     int R, int C, int bx, int by, float (*tile)[33]) {
    const int c0 = bx * 32, r0 = by * 32;
    const int x = threadIdx.x & 31, y = threadIdx.x >> 5;
#pragma unroll
    for (int k = 0; k < 4; ++k)
        tile[y + 8 * k][x] = in[(size_t)(r0 + y + 8 * k) * C + c0 + x];
    __syncthreads();
#pragma unroll
    for (int k = 0; k < 4; ++k)
        out[(size_t)(c0 + y + 8 * k) * R + r0 + x] = f2bf(tile[x][y + 8 * k]);
}

__global__ __launch_bounds__(256)
void prep_weights(const float* __restrict__ W1, const float* __restrict__ W2,
                  const float* __restrict__ Wf, const float* __restrict__ Wl,
                  const float* __restrict__ Wr, const float* __restrict__ bl,
                  u16* __restrict__ W1T, u16* __restrict__ W2T, u16* __restrict__ WfT,
                  u16* __restrict__ WlTc, u16* __restrict__ WsumT,
                  float* __restrict__ blsum, float* __restrict__ c2)
{
    __shared__ float tile[32][33];
    int id = blockIdx.x;
    if (id < 64) { tr32(W1, W1T, 256, 256, id & 7, id >> 3, tile); return; }
    id -= 64;
    if (id < 64) { tr32(W2, W2T, 256, 256, id & 7, id >> 3, tile); return; }
    id -= 64;
    if (id < 512) { tr32(Wf, WfT, 512, 1024, id & 31, id >> 5, tile); return; }
    id -= 512;
    if (id < 4608) {                       // WlTcat[t][h][e'*1024+f] = Wl[e][f][h]
        const int p = id >> 9, rem = id & 511;
        const int bx = rem & 15, by = rem >> 4;
        const int t = p / 3, ep = p % 3, e = d_eArr[t][ep];
        const int h0 = bx * 32, f0 = by * 32;
        const int x = threadIdx.x & 31, y = threadIdx.x >> 5;
        const float* src = Wl + (size_t)e * FF * HH;
#pragma unroll
        for (int k = 0; k < 4; ++k)
            tile[y + 8 * k][x] = src[(size_t)(f0 + y + 8 * k) * HH + h0 + x];
        __syncthreads();
        u16* dst = WlTc + (size_t)t * HH * 3072 + (size_t)ep * 1024;
#pragma unroll
        for (int k = 0; k < 4; ++k)
            dst[(size_t)(h0 + y + 8 * k) * 3072 + f0 + x] = f2bf(tile[x][y + 8 * k]);
        return;
    }
    id -= 4608;
    if (id < 1536) {                       // WsumT[t][h][f] = (1/3) sum Wr[e][f][h]
        const int t = id >> 9, rem = id & 511;
        const int bx = rem & 15, by = rem >> 4;
        const int h0 = bx * 32, f0 = by * 32;
        const int x = threadIdx.x & 31, y = threadIdx.x >> 5;
        const int e0 = d_eArr[t][0], e1 = d_eArr[t][1], e2 = d_eArr[t][2];
#pragma unroll
        for (int k = 0; k < 4; ++k) {
            const size_t off = (size_t)(f0 + y + 8 * k) * HH + h0 + x;
            float s = Wr[(size_t)e0 * FF * HH + off] + Wr[(size_t)e1 * FF * HH + off] +
                      Wr[(size_t)e2 * FF * HH + off];
            tile[y + 8 * k][x] = s * (1.f / 3.f);
        }
        __syncthreads();
        u16* dst = WsumT + (size_t)t * HH * FF;
#pragma unroll
        for (int k = 0; k < 4; ++k)
            dst[(size_t)(h0 + y + 8 * k) * FF + f0 + x] = f2bf(tile[x][y + 8 * k]);
        return;
    }
    // blsum (1536) + c2 (256)
#pragma unroll
    for (int j = 0; j < 6; ++j) {
        const int idx = j * 256 + threadIdx.x;
        const int t = idx >> 9, hh = idx & 511;
        blsum[t * HH + hh] = bl[d_eArr[t][0] * HH + hh] + bl[d_eArr[t][1] * HH + hh] +
                             bl[d_eArr[t][2] * HH + hh];
    }
    {
        const int d = threadIdx.x;           // c2[d] = sum_n W2[n][d]
        float s = 0.f;
        for (int n = 0; n < NN; ++n) s += W2[(size_t)n * 256 + d];
        c2[d] = s;
    }
}

// ---------------------------------------------------------------------------
// MFMA GEMM core: gl16 staging, 3-deep rotating LDS buffers, counted vmcnt.
// C[M][N] = A[M][K] * (Bt[N][K])^T (+ epilogue).
// EPI: 1 f32 beta partial | 4 bf16 + aux1[row] + fused mu (BM=256, MODE0)
//    | 5 bf16 plain | 6 f32 + aux1[row]+aux2[row]*aux3[col]
//    | 7 G5' rT out: bf16 relu(acc + beta(t,row)) with 8-partial reduce
// MODE: 0 A shared (m0=y*BM), B batched | 2 beta K-split (z=t, y=ks)
//     | 3 A batched via sB, B shared | 4 G5' dual-panel A (WsumT), B batched
// ---------------------------------------------------------------------------
template<int BM, int BN, int KLEN, int EPI, int MODE>
__global__ __launch_bounds__(256, 2)
void gemm2(const u16* __restrict__ Abase, const u16* __restrict__ Bbase,
           void* __restrict__ Cbase, const float* __restrict__ aux1,
           const float* __restrict__ aux2, const float* __restrict__ aux3,
           u16* __restrict__ muOut,
           long long sB, long long sC, int ldA, int ldB, int ldC)
{
    constexpr int WM = BM / 2, WN = BN / 2;
    constexpr int FM = WM / 16, FN = WN / 16;
    constexpr int APAN = (MODE == 4) ? 2 : 1;
    constexpr int ABY = APAN * BM * 64;
    constexpr int NIA = ABY / (16 * 256);
    constexpr int NIB = (BN * 4) / 256;
    constexpr int LPS = NIA + NIB;
    constexpr int BUFB = ABY + BN * 64;
    constexpr int NT = KLEN / 32;
    static_assert(NT >= 3, "need >=3 K-steps");
    __shared__ __align__(16) unsigned char smem[3 * BUFB];
    char* sm = (char*)smem;

    const int tid = threadIdx.x, lane = tid & 63, wave = tid >> 6;
    const int wm = wave >> 1, wn = wave & 1;
    const int n0 = blockIdx.x * BN;

    int m0 = 0, b = 0, t = 0;
    const u16* Ab = nullptr; const u16* Bb = nullptr;
    if constexpr (MODE == 0) {
        b  = blockIdx.z;
        m0 = blockIdx.y * BM;
        Ab = Abase + (size_t)m0 * ldA;
        Bb = Bbase + (size_t)b * sB + (size_t)n0 * ldB;
    } else if constexpr (MODE == 2) {     // z=t, y=ksplit
        t  = blockIdx.z;
        const int k0 = blockIdx.y * KLEN;
        Ab = Abase + (size_t)t * 64 * ldA + k0;
        Bb = Bbase + (size_t)t * (HH * 3072) + (size_t)n0 * ldB + k0;
    } else if constexpr (MODE == 3) {     // A batched (stride sB), B shared
        b  = blockIdx.z;
        m0 = blockIdx.y * BM;
        Ab = Abase + (size_t)b * sB + (size_t)m0 * ldA;
        Bb = Bbase + (size_t)n0 * ldB;
    } else {                              // MODE 4: dual-panel A, B batched
        b  = blockIdx.z;
        m0 = blockIdx.y * BM;
        Bb = Bbase + (size_t)b * sB + (size_t)n0 * ldB;
    }

    // staging addresses
    const u16* gAp[NIA]; const u16* gBp[NIB];
    int lAo[NIA], lBo[NIB];
#pragma unroll
    for (int i = 0; i < NIA; ++i) {
        const int c = i * 256 + tid;
        if constexpr (MODE == 4) {
            const int pan = c / (BM * 4), cp = c % (BM * 4);
            const int r = cp >> 2, jl = cp & 3, js = jl ^ swzv(r);
            const int tP = (blockIdx.x == 0) ? 0 : (1 + pan);
            gAp[i] = Abase + (size_t)tP * (HH * FF) + (size_t)(m0 + r) * ldA + js * 8;
        } else {
            const int r = c >> 2, jl = c & 3, js = jl ^ swzv(r);
            gAp[i] = Ab + (size_t)r * ldA + js * 8;
        }
        lAo[i] = c * 16;
    }
#pragma unroll
    for (int i = 0; i < NIB; ++i) {
        const int c = i * 256 + tid, r = c >> 2, jl = c & 3;
        gBp[i] = Bb + (size_t)r * ldB + (jl ^ swzv(r)) * 8;
        lBo[i] = ABY + c * 16;
    }
    // fragment read offsets
    const int q = lane >> 4;
    int rAo[FM], rBo[FN];
#pragma unroll
    for (int i = 0; i < FM; ++i) {
        const int r = wm * WM + i * 16 + (lane & 15);
        const int pofs = (MODE == 4) ? wn * (BM * 64) : 0;
        rAo[i] = pofs + (r * 4 + (q ^ swzv(r))) * 16;
    }
#pragma unroll
    for (int j = 0; j < FN; ++j) {
        const int r = wn * WN + j * 16 + (lane & 15);
        rBo[j] = ABY + (r * 4 + (q ^ swzv(r))) * 16;
    }

    auto stage = [&](int bufo, int it) {
        const int kofs = it * 32;
#pragma unroll
        for (int i = 0; i < NIA; ++i) gl16(gAp[i] + kofs, sm + bufo + lAo[i]);
#pragma unroll
        for (int i = 0; i < NIB; ++i) gl16(gBp[i] + kofs, sm + bufo + lBo[i]);
    };

    const f32x4 zero4 = {0.f, 0.f, 0.f, 0.f};
    f32x4 acc[FM][FN];
#pragma unroll
    for (int i = 0; i < FM; ++i)
#pragma unroll
        for (int j = 0; j < FN; ++j) acc[i][j] = zero4;

    stage(0, 0);
    stage(BUFB, 1);
    stage(2 * BUFB, 2);

    int bufo = 0;
    for (int it = 0; it < NT; ++it) {
        if (it < NT - 2)       waitvm<2 * LPS>();
        else if (it == NT - 2) waitvm<LPS>();
        else                   waitvm<0>();
        __builtin_amdgcn_s_barrier();

        bf16x8 af[FM], bq[FN];
#pragma unroll
        for (int i = 0; i < FM; ++i) af[i] = *(const bf16x8*)(sm + bufo + rAo[i]);
#pragma unroll
        for (int j = 0; j < FN; ++j) bq[j] = *(const bf16x8*)(sm + bufo + rBo[j]);
        asm volatile("s_waitcnt lgkmcnt(0)" ::: "memory");
        __builtin_amdgcn_sched_barrier(0);

        __builtin_amdgcn_s_setprio(1);
#pragma unroll
        for (int i = 0; i < FM; ++i)
#pragma unroll
            for (int j = 0; j < FN; ++j)
                acc[i][j] = __builtin_amdgcn_mfma_f32_16x16x32_bf16(af[i], bq[j], acc[i][j], 0, 0, 0);
        __builtin_amdgcn_s_setprio(0);

        __builtin_amdgcn_s_barrier();
        if (it + 3 < NT) stage(bufo, it + 3);
        bufo = (bufo == 2 * BUFB) ? 0 : bufo + BUFB;
    }

    // ---------------- epilogue ----------------
    const int q4   = q << 2;
    const int colb = n0 + wn * WN + (lane & 15);
    if constexpr (EPI == 1) {             // beta partials: [ks][t][64][512]
        float* C = (float*)Cbase + (size_t)blockIdx.y * 98304 + (size_t)t * (64 * HH);
#pragma unroll
        for (int i = 0; i < FM; ++i)
#pragma unroll
            for (int rr = 0; rr < 4; ++rr) {
                const int row = wm * WM + i * 16 + q4 + rr;
#pragma unroll
                for (int j = 0; j < FN; ++j)
                    C[(size_t)row * HH + colb + j * 16] = acc[i][j][rr];
            }
    } else if constexpr (EPI == 4) {      // bf16 + bias + fused mu (BM=256)
        u16* C = (u16*)Cbase + (size_t)b * sC;
        float t0[FN], t1[FN];
#pragma unroll
        for (int j = 0; j < FN; ++j) { t0[j] = 0.f; t1[j] = 0.f; }
#pragma unroll
        for (int i = 0; i < FM; ++i)
#pragma unroll
            for (int rr = 0; rr < 4; ++rr) {
                const int row = m0 + wm * WM + i * 16 + q4 + rr;
                const float bias = aux1[row];
#pragma unroll
                for (int j = 0; j < FN; ++j) {
                    const float hv = acc[i][j][rr] + bias;
                    C[(size_t)row * ldC + colb + j * 16] = f2bf(hv);
                    if (wm == 0)            t0[j] += hv;   // rows 0..127   = A
                    else if (i < FM / 2)    t0[j] += hv;   // rows 128..191 = B
                    else                    t1[j] += hv;   // rows 192..255 = C
                }
            }
#pragma unroll
        for (int j = 0; j < FN; ++j) {     // reduce across q-groups (rows)
            t0[j] += __shfl_xor(t0[j], 16, 64);
            t0[j] += __shfl_xor(t0[j], 32, 64);
            t1[j] += __shfl_xor(t1[j], 16, 64);
            t1[j] += __shfl_xor(t1[j], 32, 64);
        }
        if (lane < 16) {
#pragma unroll
            for (int j = 0; j < FN; ++j) {
                const int col = colb + j * 16;             // = f index
                if (wm == 0) {
                    const u16 v = f2bf(t0[j] * (1.f / 128.f));
#pragma unroll
                    for (int tt = 0; tt < 3; ++tt)
                        muOut[((size_t)tt * BB + b) * 3072 + (size_t)d_slotE[0][tt] * 1024 + col] = v;
                } else {
                    const u16 vB = f2bf(t0[j] * (1.f / 64.f));
                    const u16 vC = f2bf(t1[j] * (1.f / 64.f));
#pragma unroll
                    for (int tt = 0; tt < 3; ++tt) {
                        muOut[((size_t)tt * BB + b) * 3072 + (size_t)d_slotE[1][tt] * 1024 + col] = vB;
                        muOut[((size_t)tt * BB + b) * 3072 + (size_t)d_slotE[2][tt] * 1024 + col] = vC;
                    }
                }
            }
        }
    } else if constexpr (EPI == 5) {      // plain bf16
        u16* C = (u16*)Cbase + (size_t)b * sC;
#pragma unroll
        for (int i = 0; i < FM; ++i)
#pragma unroll
            for (int rr = 0; rr < 4; ++rr) {
                const int row = m0 + wm * WM + i * 16 + q4 + rr;
#pragma unroll
                for (int j = 0; j < FN; ++j)
                    C[(size_t)row * ldC + colb + j * 16] = f2bf(acc[i][j][rr]);
            }
    } else if constexpr (EPI == 6) {      // f32 + b2[row] + c2[row]*bf[col]
        float* C = (float*)Cbase + (size_t)b * sC;
        float bfv[FN];
#pragma unroll
        for (int j = 0; j < FN; ++j) bfv[j] = aux3[colb + j * 16];
#pragma unroll
        for (int i = 0; i < FM; ++i)
#pragma unroll
            for (int rr = 0; rr < 4; ++rr) {
                const int row = m0 + wm * WM + i * 16 + q4 + rr;
                const float bb2 = aux1[row], cc2 = aux2[row];
#pragma unroll
                for (int j = 0; j < FN; ++j)
                    C[(size_t)row * ldC + colb + j * 16] = acc[i][j][rr] + bb2 + cc2 * bfv[j];
            }
    } else {                              // EPI 7: G5' rT out + beta + relu
        u16* C = (u16*)Cbase + (size_t)b * sC;
        const int tw = (blockIdx.x == 0) ? 0 : (1 + wn);
#pragma unroll
        for (int i = 0; i < FM; ++i)
#pragma unroll
            for (int rr = 0; rr < 4; ++rr) {
                const int row = m0 + wm * WM + i * 16 + q4 + rr;   // h index
                float s = aux2[tw * HH + row];                      // blsum
#pragma unroll
                for (int ks = 0; ks < 8; ++ks)
                    s += aux1[(size_t)ks * 98304 + (size_t)tw * 32768 + (size_t)b * 512 + row];
                const float bet = s * (1.f / 3.f);
#pragma unroll
                for (int j = 0; j < FN; ++j) {
                    const float v = acc[i][j][rr] + bet;
                    C[(size_t)row * ldC + colb + j * 16] = f2bf(fmaxf(v, 0.f));
                }
            }
    }
}

// ---------------------------------------------------------------------------
extern "C" void kernel_launch(void* const* d_in, const int* in_sizes, int n_in,
                              void* d_out, int out_size, void* d_ws, size_t ws_size,
                              hipStream_t stream) {
    const float* x  = (const float*)d_in[0];
    const float* W1 = (const float*)d_in[1];
    const float* b1 = (const float*)d_in[2];
    const float* Wl = (const float*)d_in[3];
    const float* bl = (const float*)d_in[4];
    const float* Wr = (const float*)d_in[5];
    const float* Wf = (const float*)d_in[6];
    const float* bf = (const float*)d_in[7];
    const float* W2 = (const float*)d_in[8];
    const float* b2 = (const float*)d_in[9];
    float* y = (float*)d_out;

    // workspace layout (u16 elements); ws ~268 MB per fill-kernel WRITE_SIZE
    u16* wsS   = (u16*)d_ws;
    u16* xT    = wsS;                       // [64][1024][256] = 16,777,216
    u16* h     = wsS + 16777216;            // [64][256][1024] = 16,777,216
    u16* rT    = wsS + 33554432;            // [64][512][256]  =  8,388,608
    u16* W1T   = wsS + 41943040;            // [256][256]
    u16* W2T   = wsS + 42008576;            // [256][256]
    u16* WfT   = wsS + 42074112;            // [1024][512]
    u16* WsumT = wsS + 42598400;            // [3][512][1024]
    u16* WlTc  = wsS + 44171264;            // [3][512][3072]
    u16* muCat = wsS + 48889856;            // [3][64][3072]
    float* tmp8  = (float*)(wsS + 49479680);  // [8][3][64][512] f32
    float* blsum = tmp8 + 786432;             // [3][512] f32
    float* c2    = blsum + 1536;              // [256] f32
    u16* z = xT;                              // alias: xT dead after G1

    // weight prep (one launch) + x transpose
    prep_weights<<<dim3(6785), 256, 0, stream>>>(W1, W2, Wf, Wl, Wr, bl,
                                                 W1T, W2T, WfT, WlTc, WsumT, blsum, c2);
    transpose_bf16<<<dim3(32, 8, 64), 256, 0, stream>>>(x, xT, 256, 1024);

    // G1: h[b][n][s] = W1T[n][d] . xT[b][s][d] + b1[n], fused mu -> muCat
    gemm2<256, 128, 256, 4, 0><<<dim3(8, 1, 64), 256, 0, stream>>>(
        W1T, xT, h, b1, nullptr, nullptr, muCat, 262144, 262144, 256, 256, 1024);
    // beta partials: tmp8[ks][t][b][h] = muCat[t][b][kslice] . WlTc[t][h][kslice]
    gemm2<64, 64, 384, 1, 2><<<dim3(8, 8, 3), 256, 0, stream>>>(
        muCat, WlTc, tmp8, nullptr, nullptr, nullptr, nullptr, 0, 0, 3072, 3072, 512);
    // G5': rT[b][h][n] = relu( WsumT[t(n)][h][:] . h[b][n][:] + beta )
    gemm2<128, 128, 1024, 7, 4><<<dim3(2, 4, 64), 256, 0, stream>>>(
        WsumT, h, rT, tmp8, blsum, nullptr, nullptr, 262144, 131072, 1024, 1024, 256);
    // Gz: z[b][d][h] = W2T[d][:] . rT[b][h][:]
    gemm2<256, 128, 256, 5, 0><<<dim3(4, 1, 64), 256, 0, stream>>>(
        W2T, rT, z, nullptr, nullptr, nullptr, nullptr, 131072, 131072, 256, 256, 512);
    // Gy: y[b][d][s] = z[b][d][:] . WfT[s][:] + b2[d] + c2[d]*bf[s]
    gemm2<256, 128, 512, 6, 3><<<dim3(8, 1, 64), 256, 0, stream>>>(
        z, WfT, y, b2, c2, bf, nullptr, 131072, 262144, 512, 512, 1024);
}

// Round 9
// 130.694 us; speedup vs baseline: 1.1236x; 1.1236x over previous
//
#include <hip/hip_runtime.h>

typedef unsigned short u16;
typedef __attribute__((ext_vector_type(8))) short bf16x8;
typedef __attribute__((ext_vector_type(4))) float f32x4;

// Problem constants
constexpr int BB = 64;     // batch
constexpr int NN = 256;    // nodes
constexpr int SS = 1024;   // LP*P spatial (= F)
constexpr int FF = 1024;   // node feature dim
constexpr int HH = 512;    // hidden

// EDGE_TYPES = [AB,BA,AC,CA,BC,CB,AA,BB,CC]
// dst A edges {1,3,6}; dst B {0,5,7}; dst C {2,4,8}
__device__ const int d_eArr[3][3] = {{1, 3, 6}, {0, 5, 7}, {2, 4, 8}};
// muCat slot: for src type tp, (dst t) -> e' slot with src(eArr[t][e'])==tp
__device__ const int d_slotE[3][3] = {{2, 0, 0}, {0, 2, 1}, {1, 1, 2}};

__device__ __forceinline__ u16 f2bf(float f) {
    union { float f; unsigned u; } v; v.f = f;
    unsigned r = v.u + 0x7FFFu + ((v.u >> 16) & 1u);
    return (u16)(r >> 16);
}
__device__ __forceinline__ float bf2f(u16 h) {
    union { unsigned u; float f; } v; v.u = ((unsigned)h) << 16;
    return v.f;
}

typedef const __attribute__((address_space(1))) void gv_t;
typedef __attribute__((address_space(3))) void lv_t;
__device__ __forceinline__ void gl16(const void* g, void* l) {
    __builtin_amdgcn_global_load_lds((gv_t*)g, (lv_t*)l, 16, 0, 0);
}
// 16B-slot swizzle per LDS row
__device__ __forceinline__ int swzv(int r) { return (r ^ (r >> 2)) & 3; }

template<int N> __device__ __forceinline__ void waitvm();
template<> __device__ __forceinline__ void waitvm<0>()  { asm volatile("s_waitcnt vmcnt(0)" ::: "memory"); }
template<> __device__ __forceinline__ void waitvm<2>()  { asm volatile("s_waitcnt vmcnt(2)" ::: "memory"); }
template<> __device__ __forceinline__ void waitvm<4>()  { asm volatile("s_waitcnt vmcnt(4)" ::: "memory"); }
template<> __device__ __forceinline__ void waitvm<6>()  { asm volatile("s_waitcnt vmcnt(6)" ::: "memory"); }
template<> __device__ __forceinline__ void waitvm<8>()  { asm volatile("s_waitcnt vmcnt(8)" ::: "memory"); }
template<> __device__ __forceinline__ void waitvm<12>() { asm volatile("s_waitcnt vmcnt(12)" ::: "memory"); }

// G5 grouped-row decode: m-tile g -> global (b*256+n) for local row r (0..127)
__device__ __forceinline__ int g5row(int t, int g, int r) {
    if (t == 0) return (g << 8) + r;
    const int bp = (t == 1) ? (g - 64) : (g - 96);
    const int b  = (bp << 1) + (r >> 6);
    const int n  = ((t == 1) ? 128 : 192) + (r & 63);
    return (b << 8) + n;
}

// ---------------------------------------------------------------------------
// Batched transpose fp32 -> bf16: out[b][c][r] = in[b][r][c]  (x only).
// ---------------------------------------------------------------------------
__global__ __launch_bounds__(256)
void transpose_bf16(const float* __restrict__ in, u16* __restrict__ out, int R, int C) {
    __shared__ float tile[32][33];
    const int b = blockIdx.z;
    in  += (size_t)b * R * C;
    out += (size_t)b * R * C;
    const int c0 = blockIdx.x * 32, r0 = blockIdx.y * 32;
    const int x = threadIdx.x & 31, y = threadIdx.x >> 5;
#pragma unroll
    for (int k = 0; k < 4; ++k)
        tile[y + 8 * k][x] = in[(size_t)(r0 + y + 8 * k) * C + c0 + x];
    __syncthreads();
#pragma unroll
    for (int k = 0; k < 4; ++k)
        out[(size_t)(c0 + y + 8 * k) * R + r0 + x] = f2bf(tile[x][y + 8 * k]);
}

// ---------------------------------------------------------------------------
// Combined weight prep: W1T, W2T, WfT transposes + WlTcat + WsumT + blsum
// ---------------------------------------------------------------------------
__device__ __forceinline__ void tr32(const float* __restrict__ in, u16* __restrict__ out,
                                     int R, int C, int bx, int by, float (*tile)[33]) {
    const int c0 = bx * 32, r0 = by * 32;
    const int x = threadIdx.x & 31, y = threadIdx.x >> 5;
#pragma unroll
    for (int k = 0; k < 4; ++k)
        tile[y + 8 * k][x] = in[(size_t)(r0 + y + 8 * k) * C + c0 + x];
    __syncthreads();
#pragma unroll
    for (int k = 0; k < 4; ++k)
        out[(size_t)(c0 + y + 8 * k) * R + r0 + x] = f2bf(tile[x][y + 8 * k]);
}

__global__ __launch_bounds__(256)
void prep_weights(const float* __restrict__ W1, const float* __restrict__ W2,
                  const float* __restrict__ Wf, const float* __restrict__ Wl,
                  const float* __restrict__ Wr, const float* __restrict__ bl,
                  u16* __restrict__ W1T, u16* __restrict__ W2T, u16* __restrict__ WfT,
                  u16* __restrict__ WlTc, u16* __restrict__ WsumT,
                  float* __restrict__ blsum)
{
    __shared__ float tile[32][33];
    int id = blockIdx.x;
    if (id < 64) { tr32(W1, W1T, 256, 256, id & 7, id >> 3, tile); return; }
    id -= 64;
    if (id < 64) { tr32(W2, W2T, 256, 256, id & 7, id >> 3, tile); return; }
    id -= 64;
    if (id < 512) { tr32(Wf, WfT, 512, 1024, id & 31, id >> 5, tile); return; }
    id -= 512;
    if (id < 4608) {                       // WlTcat[t][h][e'*1024+f] = Wl[e][f][h]
        const int p = id >> 9, rem = id & 511;
        const int bx = rem & 15, by = rem >> 4;
        const int t = p / 3, ep = p % 3, e = d_eArr[t][ep];
        const int h0 = bx * 32, f0 = by * 32;
        const int x = threadIdx.x & 31, y = threadIdx.x >> 5;
        const float* src = Wl + (size_t)e * FF * HH;
#pragma unroll
        for (int k = 0; k < 4; ++k)
            tile[y + 8 * k][x] = src[(size_t)(f0 + y + 8 * k) * HH + h0 + x];
        __syncthreads();
        u16* dst = WlTc + (size_t)t * HH * 3072 + (size_t)ep * 1024;
#pragma unroll
        for (int k = 0; k < 4; ++k)
            dst[(size_t)(h0 + y + 8 * k) * 3072 + f0 + x] = f2bf(tile[x][y + 8 * k]);
        return;
    }
    id -= 4608;
    if (id < 1536) {                       // WsumT[t][h][f] = (1/3) sum Wr[e][f][h]
        const int t = id >> 9, rem = id & 511;
        const int bx = rem & 15, by = rem >> 4;
        const int h0 = bx * 32, f0 = by * 32;
        const int x = threadIdx.x & 31, y = threadIdx.x >> 5;
        const int e0 = d_eArr[t][0], e1 = d_eArr[t][1], e2 = d_eArr[t][2];
#pragma unroll
        for (int k = 0; k < 4; ++k) {
            const size_t off = (size_t)(f0 + y + 8 * k) * HH + h0 + x;
            float s = Wr[(size_t)e0 * FF * HH + off] + Wr[(size_t)e1 * FF * HH + off] +
                      Wr[(size_t)e2 * FF * HH + off];
            tile[y + 8 * k][x] = s * (1.f / 3.f);
        }
        __syncthreads();
        u16* dst = WsumT + (size_t)t * HH * FF;
#pragma unroll
        for (int k = 0; k < 4; ++k)
            dst[(size_t)(h0 + y + 8 * k) * FF + f0 + x] = f2bf(tile[x][y + 8 * k]);
        return;
    }
    // blsum (1536), 6 per thread
#pragma unroll
    for (int j = 0; j < 6; ++j) {
        const int idx = j * 256 + threadIdx.x;
        const int t = idx >> 9, hh = idx & 511;
        blsum[t * HH + hh] = bl[d_eArr[t][0] * HH + hh] + bl[d_eArr[t][1] * HH + hh] +
                             bl[d_eArr[t][2] * HH + hh];
    }
}

// ---------------------------------------------------------------------------
// MFMA GEMM core: gl16 staging, 3-deep rotating LDS buffers, counted vmcnt,
// LDS-staged fully-coalesced epilogue stores (no partial-line write-allocate),
// XCD-locality 1-D grid decode (same-b / same-g blocks land on one XCD).
// C[M][N] = A[M][K] * (Bt[N][K])^T (+ epilogue).
// EPI: 0 bf16 + aux1[row] | 1 f32 beta partial (direct stores, tiny)
//    | 2 G5 bf16 relu(acc+beta) grouped rows | 3 f32 + aux1[row]
//    | 4 bf16 + aux1[row] + fused mu (BM=256)
// MODE: 0 1-D grid: b=id&63, kx=id>>6, n0=(kx%NX)*BN, m0=(kx/NX)*BM; A shared
//     | 1 1-D grid: g=id&127, x=id>>7 (G5 grouped rows)
//     | 2 beta K-split (3-D grid: x=n, y=ks, z=t)
// ---------------------------------------------------------------------------
template<int BM, int BN, int KLEN, int EPI, int MODE, int NX>
__global__ __launch_bounds__(256, 2)
void gemm2(const u16* __restrict__ Abase, const u16* __restrict__ Bbase,
           void* __restrict__ Cbase, const float* __restrict__ aux1,
           const float* __restrict__ aux2, u16* __restrict__ muOut,
           long long sB, long long sC, int ldA, int ldB, int ldC)
{
    constexpr int WM = BM / 2, WN = BN / 2;
    constexpr int FM = WM / 16, FN = WN / 16;
    constexpr int NIA = (BM * 4) / 256, NIB = (BN * 4) / 256;
    constexpr int LPS = NIA + NIB;
    constexpr int BUFB = (BM + BN) * 64;
    constexpr int NT = KLEN / 32;
    static_assert(NT >= 3, "need >=3 K-steps");
    __shared__ __align__(16) unsigned char smem[3 * BUFB];
    char* sm = (char*)smem;

    const int tid = threadIdx.x, lane = tid & 63, wave = tid >> 6;
    const int wm = wave >> 1, wn = wave & 1;

    int n0 = 0, m0 = 0, b = 0, t = 0, g = 0;
    const u16* Ab = nullptr; const u16* Bb = nullptr;
    if constexpr (MODE == 0) {
        const int id = blockIdx.x;
        b  = id & 63;
        const int kx = id >> 6;
        n0 = (kx % NX) * BN;
        m0 = (kx / NX) * BM;
        Ab = Abase + (size_t)m0 * ldA;
        Bb = Bbase + (size_t)b * sB + (size_t)n0 * ldB;
    } else if constexpr (MODE == 1) {
        const int id = blockIdx.x;
        g  = id & 127;
        n0 = (id >> 7) * BN;
        t  = (g < 64) ? 0 : (g < 96 ? 1 : 2);
        Ab = Abase;
        Bb = Bbase + (size_t)t * (HH * FF) + (size_t)n0 * ldB;
    } else {                       // MODE 2: z=t, y=ksplit, x=n
        t  = blockIdx.z;
        n0 = blockIdx.x * BN;
        const int k0 = blockIdx.y * KLEN;
        Ab = Abase + (size_t)t * 64 * ldA + k0;
        Bb = Bbase + (size_t)t * (HH * 3072) + (size_t)n0 * ldB + k0;
    }

    // staging addresses: chunk c -> LDS byte c*16 (linear), global src pre-swizzled
    const u16* gAp[NIA]; const u16* gBp[NIB];
    int lAo[NIA], lBo[NIB];
#pragma unroll
    for (int i = 0; i < NIA; ++i) {
        const int c = i * 256 + tid, r = c >> 2, jl = c & 3;
        const int js = jl ^ swzv(r);
        size_t rowoff;
        if constexpr (MODE == 1) rowoff = (size_t)g5row(t, g, r) * FF;
        else                     rowoff = (size_t)r * ldA;
        gAp[i] = Ab + rowoff + js * 8;
        lAo[i] = c * 16;
    }
#pragma unroll
    for (int i = 0; i < NIB; ++i) {
        const int c = i * 256 + tid, r = c >> 2, jl = c & 3;
        gBp[i] = Bb + (size_t)r * ldB + (jl ^ swzv(r)) * 8;
        lBo[i] = BM * 64 + c * 16;
    }
    // fragment read offsets (same swizzle on read side)
    const int q = lane >> 4;
    int rAo[FM], rBo[FN];
#pragma unroll
    for (int i = 0; i < FM; ++i) {
        const int r = wm * WM + i * 16 + (lane & 15);
        rAo[i] = (r * 4 + (q ^ swzv(r))) * 16;
    }
#pragma unroll
    for (int j = 0; j < FN; ++j) {
        const int r = wn * WN + j * 16 + (lane & 15);
        rBo[j] = BM * 64 + (r * 4 + (q ^ swzv(r))) * 16;
    }

    auto stage = [&](int bufo, int it) {
        const int kofs = it * 32;
#pragma unroll
        for (int i = 0; i < NIA; ++i) gl16(gAp[i] + kofs, sm + bufo + lAo[i]);
#pragma unroll
        for (int i = 0; i < NIB; ++i) gl16(gBp[i] + kofs, sm + bufo + lBo[i]);
    };

    const f32x4 zero4 = {0.f, 0.f, 0.f, 0.f};
    f32x4 acc[FM][FN];
#pragma unroll
    for (int i = 0; i < FM; ++i)
#pragma unroll
        for (int j = 0; j < FN; ++j) acc[i][j] = zero4;

    stage(0, 0);
    stage(BUFB, 1);
    stage(2 * BUFB, 2);

    int bufo = 0;
    for (int it = 0; it < NT; ++it) {
        if (it < NT - 2)       waitvm<2 * LPS>();
        else if (it == NT - 2) waitvm<LPS>();
        else                   waitvm<0>();
        __builtin_amdgcn_s_barrier();

        bf16x8 af[FM], bq[FN];
#pragma unroll
        for (int i = 0; i < FM; ++i) af[i] = *(const bf16x8*)(sm + bufo + rAo[i]);
#pragma unroll
        for (int j = 0; j < FN; ++j) bq[j] = *(const bf16x8*)(sm + bufo + rBo[j]);
        asm volatile("s_waitcnt lgkmcnt(0)" ::: "memory");
        __builtin_amdgcn_sched_barrier(0);

        __builtin_amdgcn_s_setprio(1);
#pragma unroll
        for (int i = 0; i < FM; ++i)
#pragma unroll
            for (int j = 0; j < FN; ++j)
                acc[i][j] = __builtin_amdgcn_mfma_f32_16x16x32_bf16(af[i], bq[j], acc[i][j], 0, 0, 0);
        __builtin_amdgcn_s_setprio(0);

        __builtin_amdgcn_s_barrier();
        if (it + 3 < NT) stage(bufo, it + 3);
        bufo = (bufo == 2 * BUFB) ? 0 : bufo + BUFB;
    }
    // after the final barrier above, all waves are done with LDS -> reuse it

    // ---------------- epilogue ----------------
    const int q4 = q << 2;
    constexpr int BNP = BN + 8;           // padded LDS row stride (elements)

    if constexpr (EPI == 1) {             // beta partials (tiny): direct stores
        float* C = (float*)Cbase + (size_t)blockIdx.y * 98304 + (size_t)t * (64 * HH);
        const int colb = n0 + wn * WN + (lane & 15);
#pragma unroll
        for (int i = 0; i < FM; ++i)
#pragma unroll
            for (int rr = 0; rr < 4; ++rr) {
                const int row = wm * WM + i * 16 + q4 + rr;
#pragma unroll
                for (int j = 0; j < FN; ++j)
                    C[(size_t)row * HH + colb + j * 16] = acc[i][j][rr];
            }
    } else if constexpr (EPI == 0 || EPI == 4 || EPI == 2) {   // bf16 tile via LDS
        u16* lds = (u16*)sm;              // [BM][BNP] u16 <= 69632 B
        const int lcb = wn * WN + (lane & 15);
        float t0[FN], t1[FN];
        if constexpr (EPI == 4) {
#pragma unroll
            for (int j = 0; j < FN; ++j) { t0[j] = 0.f; t1[j] = 0.f; }
        }
        float bet[FN];
        if constexpr (EPI == 2) {         // beta per (t, b(row-block), abs col)
            const int bb = (t == 0) ? g : ((((t == 1) ? (g - 64) : (g - 96)) << 1) + wm);
#pragma unroll
            for (int j = 0; j < FN; ++j) {
                const int col = n0 + lcb + j * 16;
                float s = aux2[t * HH + col];
#pragma unroll
                for (int ks = 0; ks < 8; ++ks)
                    s += aux1[(size_t)ks * 98304 + (size_t)((t << 6) + bb) * HH + col];
                bet[j] = s * (1.f / 3.f);
            }
        }
#pragma unroll
        for (int i = 0; i < FM; ++i)
#pragma unroll
            for (int rr = 0; rr < 4; ++rr) {
                const int lrow = wm * WM + i * 16 + q4 + rr;
                float bias = 0.f;
                if constexpr (EPI == 0 || EPI == 4) bias = aux1[m0 + lrow];
#pragma unroll
                for (int j = 0; j < FN; ++j) {
                    float v = acc[i][j][rr] + ((EPI == 2) ? bet[j] : bias);
                    if constexpr (EPI == 2) v = fmaxf(v, 0.f);
                    lds[lrow * BNP + lcb + j * 16] = f2bf(v);
                    if constexpr (EPI == 4) {
                        const float hv = v;
                        if (wm == 0)            t0[j] += hv;   // rows 0..127   = A
                        else if (i < FM / 2)    t0[j] += hv;   // rows 128..191 = B
                        else                    t1[j] += hv;   // rows 192..255 = C
                    }
                }
            }
        __syncthreads();
        // coalesced copy: 16B per lane, full 128B lines
        {
            u16* Cg;
            if constexpr (EPI == 2) Cg = (u16*)Cbase;                 // row-remapped below
            else                    Cg = (u16*)Cbase + (size_t)b * sC;
            constexpr int CH = (BM * BN) / (256 * 8);
#pragma unroll
            for (int c = 0; c < CH; ++c) {
                const int e   = (c * 256 + tid) * 8;
                const int row = e / BN, col = e % BN;
                const bf16x8 v = *(const bf16x8*)&lds[row * BNP + col];
                size_t goff;
                if constexpr (EPI == 2) goff = (size_t)g5row(t, g, row) * ldC + n0 + col;
                else                    goff = (size_t)(m0 + row) * ldC + n0 + col;
                *(bf16x8*)(Cg + goff) = v;
            }
        }
        if constexpr (EPI == 4) {          // fused mu (unchanged math)
#pragma unroll
            for (int j = 0; j < FN; ++j) {
                t0[j] += __shfl_xor(t0[j], 16, 64);
                t0[j] += __shfl_xor(t0[j], 32, 64);
                t1[j] += __shfl_xor(t1[j], 16, 64);
                t1[j] += __shfl_xor(t1[j], 32, 64);
            }
            if (lane < 16) {
#pragma unroll
                for (int j = 0; j < FN; ++j) {
                    const int col = n0 + lcb + j * 16;
                    if (wm == 0) {
                        const u16 v = f2bf(t0[j] * (1.f / 128.f));
#pragma unroll
                        for (int tt = 0; tt < 3; ++tt)
                            muOut[((size_t)tt * BB + b) * 3072 + (size_t)d_slotE[0][tt] * 1024 + col] = v;
                    } else {
                        const u16 vB = f2bf(t0[j] * (1.f / 64.f));
                        const u16 vC = f2bf(t1[j] * (1.f / 64.f));
#pragma unroll
                        for (int tt = 0; tt < 3; ++tt) {
                            muOut[((size_t)tt * BB + b) * 3072 + (size_t)d_slotE[1][tt] * 1024 + col] = vB;
                            muOut[((size_t)tt * BB + b) * 3072 + (size_t)d_slotE[2][tt] * 1024 + col] = vC;
                        }
                    }
                }
            }
        }
    } else {                              // EPI 3: f32 tile via LDS, two halves
        float* lf = (float*)sm;           // [BM/2][BNP] f32 <= 69632 B
        float* Cg = (float*)Cbase + (size_t)b * sC;
        const int lcb = wn * WN + (lane & 15);
#pragma unroll
        for (int half = 0; half < 2; ++half) {
            if (wm == half) {
#pragma unroll
                for (int i = 0; i < FM; ++i)
#pragma unroll
                    for (int rr = 0; rr < 4; ++rr) {
                        const int lrow = i * 16 + q4 + rr;               // 0..WM-1
                        const float bias = aux1[m0 + half * WM + lrow];
#pragma unroll
                        for (int j = 0; j < FN; ++j)
                            lf[lrow * BNP + lcb + j * 16] = acc[i][j][rr] + bias;
                    }
            }
            __syncthreads();
            constexpr int CH = (WM * BN) / (256 * 4);
#pragma unroll
            for (int c = 0; c < CH; ++c) {
                const int e   = (c * 256 + tid) * 4;
                const int row = e / BN, col = e % BN;
                const f32x4 v = *(const f32x4*)&lf[row * BNP + col];
                *(f32x4*)(Cg + (size_t)(m0 + half * WM + row) * ldC + n0 + col) = v;
            }
            __syncthreads();
        }
    }
}

// ---------------------------------------------------------------------------
extern "C" void kernel_launch(void* const* d_in, const int* in_sizes, int n_in,
                              void* d_out, int out_size, void* d_ws, size_t ws_size,
                              hipStream_t stream) {
    const float* x  = (const float*)d_in[0];
    const float* W1 = (const float*)d_in[1];
    const float* b1 = (const float*)d_in[2];
    const float* Wl = (const float*)d_in[3];
    const float* bl = (const float*)d_in[4];
    const float* Wr = (const float*)d_in[5];
    const float* Wf = (const float*)d_in[6];
    const float* bf = (const float*)d_in[7];
    const float* W2 = (const float*)d_in[8];
    const float* b2 = (const float*)d_in[9];
    float* y = (float*)d_out;

    // workspace layout (u16 elements) — R5 layout
    u16* wsS   = (u16*)d_ws;
    u16* xT    = wsS;                       // [64][1024][256] = 16,777,216
    u16* h     = wsS + 16777216;            // [64][256][1024] = 16,777,216
    u16* r     = wsS + 33554432;            // [64][256][512]  =  8,388,608
    u16* W1T   = wsS + 41943040;            // [256][256]
    u16* W2T   = wsS + 42008576;            // [256][256]
    u16* WfT   = wsS + 42074112;            // [1024][512]
    u16* WsumT = wsS + 42598400;            // [3][512][1024]
    u16* WlTc  = wsS + 44171264;            // [3][512][3072]
    u16* muCat = wsS + 48889856;            // [3][64][3072]
    float* tmp8  = (float*)(wsS + 49479680);  // [8][3][64][512] f32
    float* blsum = tmp8 + 786432;             // [3][512] f32
    u16* outT = xT;                           // alias: xT dead after G1

    // weight prep (one launch) + x transpose
    prep_weights<<<dim3(6785), 256, 0, stream>>>(W1, W2, Wf, Wl, Wr, bl,
                                                 W1T, W2T, WfT, WlTc, WsumT, blsum);
    transpose_bf16<<<dim3(32, 8, 64), 256, 0, stream>>>(x, xT, 256, 1024);

    // G1: h[b][n][s] = W1T[n][d] . xT[b][s][d] + b1[n], fused mu -> muCat
    gemm2<256, 128, 256, 4, 0, 8><<<dim3(512), 256, 0, stream>>>(
        W1T, xT, h, b1, nullptr, muCat, 262144, 262144, 256, 256, 1024);
    // beta partials: tmp8[ks][t][b][h] = muCat[t][b][kslice] . WlTc[t][h][kslice]
    gemm2<64, 64, 384, 1, 2, 1><<<dim3(8, 8, 3), 256, 0, stream>>>(
        muCat, WlTc, tmp8, nullptr, nullptr, nullptr, 0, 0, 3072, 3072, 512);
    // G5: r[b*256+n][h] = relu( h-rows . WsumT[t(n)] + beta ), grouped rows
    gemm2<128, 128, 1024, 2, 1, 4><<<dim3(512), 256, 0, stream>>>(
        h, WsumT, r, tmp8, blsum, nullptr, 0, 0, 1024, 1024, 512);
    // G6: outT[b][f][n] = WfT[f][:] . r[b][n][:] + bf[f]
    gemm2<256, 128, 512, 0, 0, 2><<<dim3(512), 256, 0, stream>>>(
        WfT, r, outT, bf, nullptr, nullptr, 131072, 262144, 512, 512, 256);
    // G7: y[b][d][s] = W2T[d][:] . outT[b][s][:] + b2[d]
    gemm2<256, 128, 256, 3, 0, 8><<<dim3(512), 256, 0, stream>>>(
        W2T, outT, y, b2, nullptr, nullptr, 262144, 262144, 256, 256, 1024);
}

// Round 10
// 130.598 us; speedup vs baseline: 1.1245x; 1.0007x over previous
//
#include <hip/hip_runtime.h>

typedef unsigned short u16;
typedef __attribute__((ext_vector_type(8))) short bf16x8;
typedef __attribute__((ext_vector_type(4))) float f32x4;

// Problem constants
constexpr int BB = 64;     // batch
constexpr int NN = 256;    // nodes
constexpr int SS = 1024;   // LP*P spatial (= F)
constexpr int FF = 1024;   // node feature dim
constexpr int HH = 512;    // hidden

// EDGE_TYPES = [AB,BA,AC,CA,BC,CB,AA,BB,CC]
// dst A edges {1,3,6}; dst B {0,5,7}; dst C {2,4,8}
__device__ const int d_eArr[3][3] = {{1, 3, 6}, {0, 5, 7}, {2, 4, 8}};
// muCat slot: for src type tp, (dst t) -> e' slot with src(eArr[t][e'])==tp
__device__ const int d_slotE[3][3] = {{2, 0, 0}, {0, 2, 1}, {1, 1, 2}};

__device__ __forceinline__ u16 f2bf(float f) {
    union { float f; unsigned u; } v; v.f = f;
    unsigned r = v.u + 0x7FFFu + ((v.u >> 16) & 1u);
    return (u16)(r >> 16);
}
__device__ __forceinline__ float bf2f(u16 h) {
    union { unsigned u; float f; } v; v.u = ((unsigned)h) << 16;
    return v.f;
}

typedef const __attribute__((address_space(1))) void gv_t;
typedef __attribute__((address_space(3))) void lv_t;
__device__ __forceinline__ void gl16(const void* g, void* l) {
    __builtin_amdgcn_global_load_lds((gv_t*)g, (lv_t*)l, 16, 0, 0);
}
// 16B-slot swizzle per LDS row
__device__ __forceinline__ int swzv(int r) { return (r ^ (r >> 2)) & 3; }

template<int N> __device__ __forceinline__ void waitvm();
template<> __device__ __forceinline__ void waitvm<0>()  { asm volatile("s_waitcnt vmcnt(0)" ::: "memory"); }
template<> __device__ __forceinline__ void waitvm<2>()  { asm volatile("s_waitcnt vmcnt(2)" ::: "memory"); }
template<> __device__ __forceinline__ void waitvm<4>()  { asm volatile("s_waitcnt vmcnt(4)" ::: "memory"); }
template<> __device__ __forceinline__ void waitvm<6>()  { asm volatile("s_waitcnt vmcnt(6)" ::: "memory"); }
template<> __device__ __forceinline__ void waitvm<8>()  { asm volatile("s_waitcnt vmcnt(8)" ::: "memory"); }
template<> __device__ __forceinline__ void waitvm<12>() { asm volatile("s_waitcnt vmcnt(12)" ::: "memory"); }

// G5 grouped-row decode: m-tile g -> global (b*256+n) for local row r (0..127)
__device__ __forceinline__ int g5row(int t, int g, int r) {
    if (t == 0) return (g << 8) + r;
    const int bp = (t == 1) ? (g - 64) : (g - 96);
    const int b  = (bp << 1) + (r >> 6);
    const int n  = ((t == 1) ? 128 : 192) + (r & 63);
    return (b << 8) + n;
}

// ---------------------------------------------------------------------------
// Batched transpose fp32 -> bf16: out[b][c][r] = in[b][r][c]  (x only).
// ---------------------------------------------------------------------------
__global__ __launch_bounds__(256)
void transpose_bf16(const float* __restrict__ in, u16* __restrict__ out, int R, int C) {
    __shared__ float tile[32][33];
    const int b = blockIdx.z;
    in  += (size_t)b * R * C;
    out += (size_t)b * R * C;
    const int c0 = blockIdx.x * 32, r0 = blockIdx.y * 32;
    const int x = threadIdx.x & 31, y = threadIdx.x >> 5;
#pragma unroll
    for (int k = 0; k < 4; ++k)
        tile[y + 8 * k][x] = in[(size_t)(r0 + y + 8 * k) * C + c0 + x];
    __syncthreads();
#pragma unroll
    for (int k = 0; k < 4; ++k)
        out[(size_t)(c0 + y + 8 * k) * R + r0 + x] = f2bf(tile[x][y + 8 * k]);
}

// ---------------------------------------------------------------------------
// Combined weight prep: W1T, W2T, WfT transposes + WlTcat + WsumT + blsum
// ---------------------------------------------------------------------------
__device__ __forceinline__ void tr32(const float* __restrict__ in, u16* __restrict__ out,
                                     int R, int C, int bx, int by, float (*tile)[33]) {
    const int c0 = bx * 32, r0 = by * 32;
    const int x = threadIdx.x & 31, y = threadIdx.x >> 5;
#pragma unroll
    for (int k = 0; k < 4; ++k)
        tile[y + 8 * k][x] = in[(size_t)(r0 + y + 8 * k) * C + c0 + x];
    __syncthreads();
#pragma unroll
    for (int k = 0; k < 4; ++k)
        out[(size_t)(c0 + y + 8 * k) * R + r0 + x] = f2bf(tile[x][y + 8 * k]);
}

__global__ __launch_bounds__(256)
void prep_weights(const float* __restrict__ W1, const float* __restrict__ W2,
                  const float* __restrict__ Wf, const float* __restrict__ Wl,
                  const float* __restrict__ Wr, const float* __restrict__ bl,
                  u16* __restrict__ W1T, u16* __restrict__ W2T, u16* __restrict__ WfT,
                  u16* __restrict__ WlTc, u16* __restrict__ WsumT,
                  float* __restrict__ blsum)
{
    __shared__ float tile[32][33];
    int id = blockIdx.x;
    if (id < 64) { tr32(W1, W1T, 256, 256, id & 7, id >> 3, tile); return; }
    id -= 64;
    if (id < 64) { tr32(W2, W2T, 256, 256, id & 7, id >> 3, tile); return; }
    id -= 64;
    if (id < 512) { tr32(Wf, WfT, 512, 1024, id & 31, id >> 5, tile); return; }
    id -= 512;
    if (id < 4608) {                       // WlTcat[t][h][e'*1024+f] = Wl[e][f][h]
        const int p = id >> 9, rem = id & 511;
        const int bx = rem & 15, by = rem >> 4;
        const int t = p / 3, ep = p % 3, e = d_eArr[t][ep];
        const int h0 = bx * 32, f0 = by * 32;
        const int x = threadIdx.x & 31, y = threadIdx.x >> 5;
        const float* src = Wl + (size_t)e * FF * HH;
#pragma unroll
        for (int k = 0; k < 4; ++k)
            tile[y + 8 * k][x] = src[(size_t)(f0 + y + 8 * k) * HH + h0 + x];
        __syncthreads();
        u16* dst = WlTc + (size_t)t * HH * 3072 + (size_t)ep * 1024;
#pragma unroll
        for (int k = 0; k < 4; ++k)
            dst[(size_t)(h0 + y + 8 * k) * 3072 + f0 + x] = f2bf(tile[x][y + 8 * k]);
        return;
    }
    id -= 4608;
    if (id < 1536) {                       // WsumT[t][h][f] = (1/3) sum Wr[e][f][h]
        const int t = id >> 9, rem = id & 511;
        const int bx = rem & 15, by = rem >> 4;
        const int h0 = bx * 32, f0 = by * 32;
        const int x = threadIdx.x & 31, y = threadIdx.x >> 5;
        const int e0 = d_eArr[t][0], e1 = d_eArr[t][1], e2 = d_eArr[t][2];
#pragma unroll
        for (int k = 0; k < 4; ++k) {
            const size_t off = (size_t)(f0 + y + 8 * k) * HH + h0 + x;
            float s = Wr[(size_t)e0 * FF * HH + off] + Wr[(size_t)e1 * FF * HH + off] +
                      Wr[(size_t)e2 * FF * HH + off];
            tile[y + 8 * k][x] = s * (1.f / 3.f);
        }
        __syncthreads();
        u16* dst = WsumT + (size_t)t * HH * FF;
#pragma unroll
        for (int k = 0; k < 4; ++k)
            dst[(size_t)(h0 + y + 8 * k) * FF + f0 + x] = f2bf(tile[x][y + 8 * k]);
        return;
    }
    // blsum (1536), 6 per thread
#pragma unroll
    for (int j = 0; j < 6; ++j) {
        const int idx = j * 256 + threadIdx.x;
        const int t = idx >> 9, hh = idx & 511;
        blsum[t * HH + hh] = bl[d_eArr[t][0] * HH + hh] + bl[d_eArr[t][1] * HH + hh] +
                             bl[d_eArr[t][2] * HH + hh];
    }
}

// ---------------------------------------------------------------------------
// MFMA GEMM core: gl16 staging, 3-deep rotating LDS buffers, counted vmcnt,
// LDS-staged fully-coalesced epilogue stores, XCD-locality 1-D grid decode.
// C[M][N] = A[M][K] * (Bt[N][K])^T (+ epilogue).
// EPI: 0 bf16 + aux1[row] | 1 f32 beta partial (direct stores, tiny)
//    | 2 G5 bf16 relu(acc+beta) grouped rows | 3 f32 + aux1[row]
//    | 4 bf16 + aux1[row] + split fused mu (BM=128: m0=0 -> type A via
//      cross-wave LDS reduce; m0=128 -> wm0=B, wm1=C direct)
// MODE: 0 1-D grid: b=id&63, kx=id>>6, n0=(kx%NX)*BN, m0=(kx/NX)*BM; A shared
//     | 1 1-D grid: g=id&127, x=id>>7 (G5 grouped rows)
//     | 2 beta K-split (3-D grid: x=n, y=ks, z=t)
// ---------------------------------------------------------------------------
template<int BM, int BN, int KLEN, int EPI, int MODE, int NX>
__global__ __launch_bounds__(256, 2)
void gemm2(const u16* __restrict__ Abase, const u16* __restrict__ Bbase,
           void* __restrict__ Cbase, const float* __restrict__ aux1,
           const float* __restrict__ aux2, u16* __restrict__ muOut,
           long long sB, long long sC, int ldA, int ldB, int ldC)
{
    constexpr int WM = BM / 2, WN = BN / 2;
    constexpr int FM = WM / 16, FN = WN / 16;
    constexpr int NIA = (BM * 4) / 256, NIB = (BN * 4) / 256;
    constexpr int LPS = NIA + NIB;
    constexpr int BUFB = (BM + BN) * 64;
    constexpr int NT = KLEN / 32;
    static_assert(NT >= 3, "need >=3 K-steps");
    __shared__ __align__(16) unsigned char smem[3 * BUFB];
    char* sm = (char*)smem;

    const int tid = threadIdx.x, lane = tid & 63, wave = tid >> 6;
    const int wm = wave >> 1, wn = wave & 1;

    int n0 = 0, m0 = 0, b = 0, t = 0, g = 0;
    const u16* Ab = nullptr; const u16* Bb = nullptr;
    if constexpr (MODE == 0) {
        const int id = blockIdx.x;
        b  = id & 63;
        const int kx = id >> 6;
        n0 = (kx % NX) * BN;
        m0 = (kx / NX) * BM;
        Ab = Abase + (size_t)m0 * ldA;
        Bb = Bbase + (size_t)b * sB + (size_t)n0 * ldB;
    } else if constexpr (MODE == 1) {
        const int id = blockIdx.x;
        g  = id & 127;
        n0 = (id >> 7) * BN;
        t  = (g < 64) ? 0 : (g < 96 ? 1 : 2);
        Ab = Abase;
        Bb = Bbase + (size_t)t * (HH * FF) + (size_t)n0 * ldB;
    } else {                       // MODE 2: z=t, y=ksplit, x=n
        t  = blockIdx.z;
        n0 = blockIdx.x * BN;
        const int k0 = blockIdx.y * KLEN;
        Ab = Abase + (size_t)t * 64 * ldA + k0;
        Bb = Bbase + (size_t)t * (HH * 3072) + (size_t)n0 * ldB + k0;
    }

    // staging addresses: chunk c -> LDS byte c*16 (linear), global src pre-swizzled
    const u16* gAp[NIA]; const u16* gBp[NIB];
    int lAo[NIA], lBo[NIB];
#pragma unroll
    for (int i = 0; i < NIA; ++i) {
        const int c = i * 256 + tid, r = c >> 2, jl = c & 3;
        const int js = jl ^ swzv(r);
        size_t rowoff;
        if constexpr (MODE == 1) rowoff = (size_t)g5row(t, g, r) * FF;
        else                     rowoff = (size_t)r * ldA;
        gAp[i] = Ab + rowoff + js * 8;
        lAo[i] = c * 16;
    }
#pragma unroll
    for (int i = 0; i < NIB; ++i) {
        const int c = i * 256 + tid, r = c >> 2, jl = c & 3;
        gBp[i] = Bb + (size_t)r * ldB + (jl ^ swzv(r)) * 8;
        lBo[i] = BM * 64 + c * 16;
    }
    // fragment read offsets (same swizzle on read side)
    const int q = lane >> 4;
    int rAo[FM], rBo[FN];
#pragma unroll
    for (int i = 0; i < FM; ++i) {
        const int r = wm * WM + i * 16 + (lane & 15);
        rAo[i] = (r * 4 + (q ^ swzv(r))) * 16;
    }
#pragma unroll
    for (int j = 0; j < FN; ++j) {
        const int r = wn * WN + j * 16 + (lane & 15);
        rBo[j] = BM * 64 + (r * 4 + (q ^ swzv(r))) * 16;
    }

    auto stage = [&](int bufo, int it) {
        const int kofs = it * 32;
#pragma unroll
        for (int i = 0; i < NIA; ++i) gl16(gAp[i] + kofs, sm + bufo + lAo[i]);
#pragma unroll
        for (int i = 0; i < NIB; ++i) gl16(gBp[i] + kofs, sm + bufo + lBo[i]);
    };

    const f32x4 zero4 = {0.f, 0.f, 0.f, 0.f};
    f32x4 acc[FM][FN];
#pragma unroll
    for (int i = 0; i < FM; ++i)
#pragma unroll
        for (int j = 0; j < FN; ++j) acc[i][j] = zero4;

    stage(0, 0);
    stage(BUFB, 1);
    stage(2 * BUFB, 2);

    int bufo = 0;
    for (int it = 0; it < NT; ++it) {
        if (it < NT - 2)       waitvm<2 * LPS>();
        else if (it == NT - 2) waitvm<LPS>();
        else                   waitvm<0>();
        __builtin_amdgcn_s_barrier();

        bf16x8 af[FM], bq[FN];
#pragma unroll
        for (int i = 0; i < FM; ++i) af[i] = *(const bf16x8*)(sm + bufo + rAo[i]);
#pragma unroll
        for (int j = 0; j < FN; ++j) bq[j] = *(const bf16x8*)(sm + bufo + rBo[j]);
        asm volatile("s_waitcnt lgkmcnt(0)" ::: "memory");
        __builtin_amdgcn_sched_barrier(0);

        __builtin_amdgcn_s_setprio(1);
#pragma unroll
        for (int i = 0; i < FM; ++i)
#pragma unroll
            for (int j = 0; j < FN; ++j)
                acc[i][j] = __builtin_amdgcn_mfma_f32_16x16x32_bf16(af[i], bq[j], acc[i][j], 0, 0, 0);
        __builtin_amdgcn_s_setprio(0);

        __builtin_amdgcn_s_barrier();
        if (it + 3 < NT) stage(bufo, it + 3);
        bufo = (bufo == 2 * BUFB) ? 0 : bufo + BUFB;
    }
    // after the final barrier above, all waves are done with LDS -> reuse it

    // ---------------- epilogue ----------------
    const int q4 = q << 2;
    constexpr int BNP = BN + 8;           // padded LDS row stride (elements)

    if constexpr (EPI == 1) {             // beta partials (tiny): direct stores
        float* C = (float*)Cbase + (size_t)blockIdx.y * 98304 + (size_t)t * (64 * HH);
        const int colb = n0 + wn * WN + (lane & 15);
#pragma unroll
        for (int i = 0; i < FM; ++i)
#pragma unroll
            for (int rr = 0; rr < 4; ++rr) {
                const int row = wm * WM + i * 16 + q4 + rr;
#pragma unroll
                for (int j = 0; j < FN; ++j)
                    C[(size_t)row * HH + colb + j * 16] = acc[i][j][rr];
            }
    } else if constexpr (EPI == 0 || EPI == 2) {   // bf16 tile via LDS
        u16* lds = (u16*)sm;              // [BM][BNP] u16
        const int lcb = wn * WN + (lane & 15);
        float bet[FN];
        if constexpr (EPI == 2) {         // beta per (t, b(row-block), abs col)
            const int bb = (t == 0) ? g : ((((t == 1) ? (g - 64) : (g - 96)) << 1) + wm);
#pragma unroll
            for (int j = 0; j < FN; ++j) {
                const int col = n0 + lcb + j * 16;
                float s = aux2[t * HH + col];
#pragma unroll
                for (int ks = 0; ks < 8; ++ks)
                    s += aux1[(size_t)ks * 98304 + (size_t)((t << 6) + bb) * HH + col];
                bet[j] = s * (1.f / 3.f);
            }
        }
#pragma unroll
        for (int i = 0; i < FM; ++i)
#pragma unroll
            for (int rr = 0; rr < 4; ++rr) {
                const int lrow = wm * WM + i * 16 + q4 + rr;
                float bias = 0.f;
                if constexpr (EPI == 0) bias = aux1[m0 + lrow];
#pragma unroll
                for (int j = 0; j < FN; ++j) {
                    float v = acc[i][j][rr] + ((EPI == 2) ? bet[j] : bias);
                    if constexpr (EPI == 2) v = fmaxf(v, 0.f);
                    lds[lrow * BNP + lcb + j * 16] = f2bf(v);
                }
            }
        __syncthreads();
        {
            u16* Cg;
            if constexpr (EPI == 2) Cg = (u16*)Cbase;
            else                    Cg = (u16*)Cbase + (size_t)b * sC;
            constexpr int CH = (BM * BN) / (256 * 8);
#pragma unroll
            for (int c = 0; c < CH; ++c) {
                const int e   = (c * 256 + tid) * 8;
                const int row = e / BN, col = e % BN;
                const bf16x8 v = *(const bf16x8*)&lds[row * BNP + col];
                size_t goff;
                if constexpr (EPI == 2) goff = (size_t)g5row(t, g, row) * ldC + n0 + col;
                else                    goff = (size_t)(m0 + row) * ldC + n0 + col;
                *(bf16x8*)(Cg + goff) = v;
            }
        }
    } else if constexpr (EPI == 4) {      // bf16 + bias + split fused mu (BM=128)
        u16* lds = (u16*)sm;              // [128][136] u16 = 34816 B
        float* mubuf = (float*)(sm + 36864);   // [2 wm][128 cols] f32 = 1 KB
        const int lcb = wn * WN + (lane & 15);
        float t0[FN];
#pragma unroll
        for (int j = 0; j < FN; ++j) t0[j] = 0.f;
#pragma unroll
        for (int i = 0; i < FM; ++i)
#pragma unroll
            for (int rr = 0; rr < 4; ++rr) {
                const int lrow = wm * WM + i * 16 + q4 + rr;
                const float bias = aux1[m0 + lrow];
#pragma unroll
                for (int j = 0; j < FN; ++j) {
                    const float v = acc[i][j][rr] + bias;
                    lds[lrow * BNP + lcb + j * 16] = f2bf(v);
                    t0[j] += v;
                }
            }
#pragma unroll
        for (int j = 0; j < FN; ++j) {    // reduce across q-groups (16 rows -> 64)
            t0[j] += __shfl_xor(t0[j], 16, 64);
            t0[j] += __shfl_xor(t0[j], 32, 64);
        }
        if (m0 == 0 && lane < 16) {       // stash per-wm partial for type A
#pragma unroll
            for (int j = 0; j < FN; ++j)
                mubuf[wm * 128 + lcb + j * 16] = t0[j];
        }
        __syncthreads();
        {   // coalesced h-tile store
            u16* Cg = (u16*)Cbase + (size_t)b * sC;
            constexpr int CH = (BM * BN) / (256 * 8);
#pragma unroll
            for (int c = 0; c < CH; ++c) {
                const int e   = (c * 256 + tid) * 8;
                const int row = e / BN, col = e % BN;
                const bf16x8 v = *(const bf16x8*)&lds[row * BNP + col];
                *(bf16x8*)(Cg + (size_t)(m0 + row) * ldC + n0 + col) = v;
            }
        }
        if (m0 == 0) {                    // type A: combine wm0+wm1, /128
            if (wm == 0 && lane < 16) {
#pragma unroll
                for (int j = 0; j < FN; ++j) {
                    const int lcol = lcb + j * 16;
                    const int col  = n0 + lcol;
                    const u16 v = f2bf((mubuf[lcol] + mubuf[128 + lcol]) * (1.f / 128.f));
#pragma unroll
                    for (int tt = 0; tt < 3; ++tt)
                        muOut[((size_t)tt * BB + b) * 3072 + (size_t)d_slotE[0][tt] * 1024 + col] = v;
                }
            }
        } else {                          // m0=128: wm0 = type B, wm1 = type C
            if (lane < 16) {
                const int tp = 1 + wm;
#pragma unroll
                for (int j = 0; j < FN; ++j) {
                    const int col = n0 + lcb + j * 16;
                    const u16 v = f2bf(t0[j] * (1.f / 64.f));
#pragma unroll
                    for (int tt = 0; tt < 3; ++tt)
                        muOut[((size_t)tt * BB + b) * 3072 + (size_t)d_slotE[tp][tt] * 1024 + col] = v;
                }
            }
        }
    } else {                              // EPI 3: f32 tile via LDS, two halves
        float* lf = (float*)sm;           // [BM/2][BNP] f32
        float* Cg = (float*)Cbase + (size_t)b * sC;
        const int lcb = wn * WN + (lane & 15);
#pragma unroll
        for (int half = 0; half < 2; ++half) {
            if (wm == half) {
#pragma unroll
                for (int i = 0; i < FM; ++i)
#pragma unroll
                    for (int rr = 0; rr < 4; ++rr) {
                        const int lrow = i * 16 + q4 + rr;               // 0..WM-1
                        const float bias = aux1[m0 + half * WM + lrow];
#pragma unroll
                        for (int j = 0; j < FN; ++j)
                            lf[lrow * BNP + lcb + j * 16] = acc[i][j][rr] + bias;
                    }
            }
            __syncthreads();
            constexpr int CH = (WM * BN) / (256 * 4);
#pragma unroll
            for (int c = 0; c < CH; ++c) {
                const int e   = (c * 256 + tid) * 4;
                const int row = e / BN, col = e % BN;
                const f32x4 v = *(const f32x4*)&lf[row * BNP + col];
                *(f32x4*)(Cg + (size_t)(m0 + half * WM + row) * ldC + n0 + col) = v;
            }
            __syncthreads();
        }
    }
}

// ---------------------------------------------------------------------------
extern "C" void kernel_launch(void* const* d_in, const int* in_sizes, int n_in,
                              void* d_out, int out_size, void* d_ws, size_t ws_size,
                              hipStream_t stream) {
    const float* x  = (const float*)d_in[0];
    const float* W1 = (const float*)d_in[1];
    const float* b1 = (const float*)d_in[2];
    const float* Wl = (const float*)d_in[3];
    const float* bl = (const float*)d_in[4];
    const float* Wr = (const float*)d_in[5];
    const float* Wf = (const float*)d_in[6];
    const float* bf = (const float*)d_in[7];
    const float* W2 = (const float*)d_in[8];
    const float* b2 = (const float*)d_in[9];
    float* y = (float*)d_out;

    // workspace layout (u16 elements)
    u16* wsS   = (u16*)d_ws;
    u16* xT    = wsS;                       // [64][1024][256] = 16,777,216
    u16* h     = wsS + 16777216;            // [64][256][1024] = 16,777,216
    u16* r     = wsS + 33554432;            // [64][256][512]  =  8,388,608
    u16* W1T   = wsS + 41943040;            // [256][256]
    u16* W2T   = wsS + 42008576;            // [256][256]
    u16* WfT   = wsS + 42074112;            // [1024][512]
    u16* WsumT = wsS + 42598400;            // [3][512][1024]
    u16* WlTc  = wsS + 44171264;            // [3][512][3072]
    u16* muCat = wsS + 48889856;            // [3][64][3072]
    float* tmp8  = (float*)(wsS + 49479680);  // [8][3][64][512] f32
    float* blsum = tmp8 + 786432;             // [3][512] f32
    u16* outT = xT;                           // alias: xT dead after G1

    // weight prep (one launch) + x transpose
    prep_weights<<<dim3(6785), 256, 0, stream>>>(W1, W2, Wf, Wl, Wr, bl,
                                                 W1T, W2T, WfT, WlTc, WsumT, blsum);
    transpose_bf16<<<dim3(32, 8, 64), 256, 0, stream>>>(x, xT, 256, 1024);

    // G1: h[b][n][s] = W1T[n][d] . xT[b][s][d] + b1[n], split fused mu -> muCat
    // BM=128: 48KB LDS -> 3 blocks/CU (R9 post-mortem: BM=256's 72KB capped at 2)
    gemm2<128, 128, 256, 4, 0, 8><<<dim3(1024), 256, 0, stream>>>(
        W1T, xT, h, b1, nullptr, muCat, 262144, 262144, 256, 256, 1024);
    // beta partials: tmp8[ks][t][b][h] = muCat[t][b][kslice] . WlTc[t][h][kslice]
    gemm2<64, 64, 384, 1, 2, 1><<<dim3(8, 8, 3), 256, 0, stream>>>(
        muCat, WlTc, tmp8, nullptr, nullptr, nullptr, 0, 0, 3072, 3072, 512);
    // G5: r[b*256+n][h] = relu( h-rows . WsumT[t(n)] + beta ), grouped rows
    gemm2<128, 128, 1024, 2, 1, 4><<<dim3(512), 256, 0, stream>>>(
        h, WsumT, r, tmp8, blsum, nullptr, 0, 0, 1024, 1024, 512);
    // G6: outT[b][f][n] = WfT[f][:] . r[b][n][:] + bf[f]
    gemm2<256, 128, 512, 0, 0, 2><<<dim3(512), 256, 0, stream>>>(
        WfT, r, outT, bf, nullptr, nullptr, 131072, 262144, 512, 512, 256);
    // G7: y[b][d][s] = W2T[d][:] . outT[b][s][:] + b2[d]
    gemm2<256, 128, 256, 3, 0, 8><<<dim3(512), 256, 0, stream>>>(
        W2T, outT, y, b2, nullptr, nullptr, 262144, 262144, 256, 256, 1024);
}